// Round 3
// baseline (561.232 us; speedup 1.0000x reference)
//
#include <hip/hip_runtime.h>
#include <stdint.h>

// CoLA encoder layer, fused, v3.
//   S = x@M + s0,  M = W_Q^T C_K/32  (Q-GEMM folded away)
//   LN1 folded into conv GEMM: conv = rinv*(h'@(g1*Wc)^T) - rinv*mean*u + vb
// v3: 32 tokens/block, 8 waves, 78KB LDS -> 2 blocks/CU so independent
// blocks overlap memory and compute phases. Final store fully coalesced
// (1KB/line per wave-instruction) via bf16 staging of r in xs.

#define NT 512   // 8 waves

typedef float  f32x4  __attribute__((ext_vector_type(4)));
typedef short  s16x8  __attribute__((ext_vector_type(8)));
typedef short  s16x4  __attribute__((ext_vector_type(4)));
typedef __bf16 bf16x8 __attribute__((ext_vector_type(8)));

__device__ __forceinline__ uint16_t f2bf(float f) {
  uint32_t b = __builtin_bit_cast(uint32_t, f);
  b += 0x7FFFu + ((b >> 16) & 1u);
  return (uint16_t)(b >> 16);
}
__device__ __forceinline__ float bf2f(uint16_t u) {
  return __builtin_bit_cast(float, ((uint32_t)u) << 16);
}
__device__ __forceinline__ f32x4 MFMA(s16x8 a, s16x8 b, f32x4 c) {
  return __builtin_amdgcn_mfma_f32_16x16x32_bf16(
      __builtin_bit_cast(bf16x8, a), __builtin_bit_cast(bf16x8, b), c, 0, 0, 0);
}

// ---------------- merged preprocessing (one launch) ----------------
__global__ void k0_all(const float* __restrict__ WQ, const float* __restrict__ bQ,
                       const float* __restrict__ CK, const float* __restrict__ CV,
                       const float* __restrict__ Wc, const float* __restrict__ g1,
                       const float* __restrict__ be1, const float* __restrict__ bc,
                       uint16_t* __restrict__ MbfT, float* __restrict__ s0,
                       uint16_t* __restrict__ CVbf, uint16_t* __restrict__ Wpbf,
                       float* __restrict__ u, float* __restrict__ vb) {
  __shared__ float sm[2560];
  const int b = blockIdx.x, t = threadIdx.x;
  if (b < 64) {
    float (*wq)[16] = (float(*)[16])sm;
    float (*ck)[64] = (float(*)[64])(sm + 512);
    const int d0 = b * 16, a = t >> 2, dq = t & 3;
    float acc[4] = {0.f, 0.f, 0.f, 0.f};
    for (int e0 = 0; e0 < 1024; e0 += 32) {
      {
        int i0 = t * 2, r = i0 >> 4, c = i0 & 15;
        float2 v = *(const float2*)(WQ + (size_t)(e0 + r) * 1024 + d0 + c);
        wq[r][c] = v.x; wq[r][c + 1] = v.y;
      }
#pragma unroll
      for (int j = 0; j < 8; j++) {
        int idx = t + j * 256, r = idx >> 6, c = idx & 63;
        ck[r][c] = CK[(size_t)(e0 + r) * 64 + c];
      }
      __syncthreads();
      for (int r = 0; r < 32; r++) {
        float cv = ck[r][a];
#pragma unroll
        for (int i = 0; i < 4; i++) acc[i] += cv * wq[r][dq * 4 + i];
      }
      __syncthreads();
    }
#pragma unroll
    for (int i = 0; i < 4; i++)
      MbfT[(size_t)a * 1024 + d0 + dq * 4 + i] = f2bf(acc[i] * 0.03125f);
  } else if (b < 1152) {
    int i4 = (b - 64) * 256 + t;
    if (i4 < 16384) {
      float4 v = ((const float4*)CV)[i4];
      uint2 pk;
      pk.x = (uint32_t)f2bf(v.x) | ((uint32_t)f2bf(v.y) << 16);
      pk.y = (uint32_t)f2bf(v.z) | ((uint32_t)f2bf(v.w) << 16);
      *(uint2*)(CVbf + (size_t)i4 * 4) = pk;
    } else {
      int f4 = i4 - 16384;
      int d = (f4 * 4) & 1023;
      float4 v = ((const float4*)Wc)[f4];
      float4 g = *(const float4*)(g1 + d);
      v.x *= g.x; v.y *= g.y; v.z *= g.z; v.w *= g.w;
      uint2 pk;
      pk.x = (uint32_t)f2bf(v.x) | ((uint32_t)f2bf(v.y) << 16);
      pk.y = (uint32_t)f2bf(v.z) | ((uint32_t)f2bf(v.w) << 16);
      *(uint2*)(Wpbf + (size_t)f4 * 4) = pk;
    }
  } else if (b == 1152) {
    float (*part)[64] = (float(*)[64])sm;
    const int a = t & 63, q = t >> 6;
    float s = 0.f;
    for (int e = q * 256; e < (q + 1) * 256; e++) s += bQ[e] * CK[(size_t)e * 64 + a];
    part[q][a] = s;
    __syncthreads();
    if (q == 0) s0[a] = (part[0][a] + part[1][a] + part[2][a] + part[3][a]) * 0.03125f;
  } else {
    const int e = (b - 1153) * 4 + (t >> 6), l = t & 63;
    float su = 0.f, sv = 0.f;
#pragma unroll
    for (int j = 0; j < 16; j++) {
      int d = l + 64 * j;
      float w = Wc[(size_t)e * 1024 + d];
      su += g1[d] * w;
      sv += be1[d] * w;
    }
#pragma unroll
    for (int m = 1; m <= 32; m <<= 1) { su += __shfl_xor(su, m); sv += __shfl_xor(sv, m); }
    if (l == 0) { u[e] = su; vb[e] = sv + bc[e]; }
  }
}

// ---------------- main fused kernel ----------------
// grid 1024, block 512 (8 waves), 32 tokens/block, dyn LDS 78080 B (2 blk/CU):
//   xs    [32 tok][1024] bf16, XOR-swizzle byte^=(tok&7)<<4   @0       65536
//   asmb  [32 tok][64 a] bf16, same swizzle                   @65536    4096
//   Ssm   f32 [64 a][stride 33]  (dead after softmax)         @69632    8448
//   part  float2[8 w][32 tok]   (overlays Ssm)                @69632    2048
//   stats float [32 tok][2]     (overlays Ssm+2048)           @71680     256
__global__ __launch_bounds__(NT, 4) void fused_main(
    const float* __restrict__ x, const int* __restrict__ mask,
    const float* __restrict__ s0, const uint16_t* __restrict__ MbfT,
    const uint16_t* __restrict__ CVbf, const uint16_t* __restrict__ Wpbf,
    const float* __restrict__ u, const float* __restrict__ vb,
    const float* __restrict__ g1, const float* __restrict__ be1,
    const float* __restrict__ g2, const float* __restrict__ be2,
    float* __restrict__ out) {
  extern __shared__ char smem[];
  char*   xs    = smem;
  char*   asmb  = smem + 65536;
  float*  Ssm   = (float*)(smem + 69632);     // [64][33]
  float2* part  = (float2*)(smem + 69632);    // [8][32]
  float*  stats = (float*)(smem + 71680);     // [32][2]

  const int tid = threadIdx.x;
  const int w = tid >> 6, l = tid & 63;
  const int ln = l & 15, kg = l >> 4;
  const size_t tok0 = (size_t)blockIdx.x * 32;
  const int E0 = w * 128;   // this wave's 128-feature slice (8 tiles of 16)

  // ---- P1: x -> bf16 swizzled LDS (4096 16B-granules, 8/thread)
  {
    const float* xg = x + tok0 * 1024;
#pragma unroll
    for (int i = 0; i < 8; i++) {
      int g = tid + i * NT;
      int row = g >> 7, c8 = g & 127;
      const float4* p = (const float4*)(xg + (size_t)row * 1024 + c8 * 8);
      float vbuf[8];
      *(float4*)(vbuf) = p[0]; *(float4*)(vbuf + 4) = p[1];
      s16x8 pk;
#pragma unroll
      for (int e = 0; e < 8; e++) pk[e] = (short)f2bf(vbuf[e]);
      uint32_t ad = (uint32_t)(row * 2048 + c8 * 16) ^ ((uint32_t)(row & 7) << 4);
      *(s16x8*)(xs + ad) = pk;
    }
  }
  __syncthreads();

  // ---- P2: S'[a][tok] = M @ x^T (+s0); wave w: a-tile=w&3, tok-tile=w>>2
  {
    const int at = w & 3, tt = w >> 2;
    const int tokr = tt * 16 + ln;
    f32x4 accs = {0.f, 0.f, 0.f, 0.f};
    for (int ks = 0; ks < 32; ks++) {
      uint32_t ad = (uint32_t)(tokr * 2048 + ks * 64 + kg * 16) ^ ((uint32_t)(tokr & 7) << 4);
      s16x8 bfr = *(const s16x8*)(xs + ad);
      s16x8 af = *(const s16x8*)(MbfT + (size_t)(at * 16 + ln) * 1024 + ks * 32 + kg * 8);
      accs = MFMA(af, bfr, accs);
    }
    float4 s4 = *(const float4*)(s0 + at * 16 + kg * 4);
    const float* sp = (const float*)&s4;
#pragma unroll
    for (int r = 0; r < 4; r++)
      Ssm[(at * 16 + kg * 4 + r) * 33 + tokr] = accs[r] + sp[r];
  }
  __syncthreads();

  // ---- P3: softmax over a (threads 0..255, 8/token) -> asmb bf16 swizzled
  if (tid < 256) {
    int token = tid >> 3, g8 = tid & 7;
    float v[8];
#pragma unroll
    for (int i = 0; i < 8; i++) v[i] = Ssm[(g8 * 8 + i) * 33 + token];
    float m = v[0];
#pragma unroll
    for (int i = 1; i < 8; i++) m = fmaxf(m, v[i]);
    m = fmaxf(m, __shfl_xor(m, 1));
    m = fmaxf(m, __shfl_xor(m, 2));
    m = fmaxf(m, __shfl_xor(m, 4));
    float s = 0.f;
#pragma unroll
    for (int i = 0; i < 8; i++) { v[i] = __expf(v[i] - m); s += v[i]; }
    s += __shfl_xor(s, 1); s += __shfl_xor(s, 2); s += __shfl_xor(s, 4);
    float inv = (float)mask[tok0 + token] / s;
    s16x8 pk;
#pragma unroll
    for (int i = 0; i < 8; i++) pk[i] = (short)f2bf(v[i] * inv);
    uint32_t ad = (uint32_t)(token * 128 + g8 * 16) ^ ((uint32_t)(token & 7) << 4);
    *(s16x8*)(asmb + ad) = pk;
  }
  __syncthreads();

  // ---- P4: attn'[d][tok] = C_V @ A^T (K=64); wave owns d in [E0,E0+128)
  float st[2], sq[2];
  {
    f32x4 acc[8][2];
#pragma unroll
    for (int et = 0; et < 8; et++)
#pragma unroll
      for (int tt = 0; tt < 2; tt++) acc[et][tt] = f32x4{0.f, 0.f, 0.f, 0.f};
#pragma unroll
    for (int ks = 0; ks < 2; ks++) {
      s16x8 bfr[2];
#pragma unroll
      for (int tt = 0; tt < 2; tt++) {
        int tokr = tt * 16 + ln;
        uint32_t ad = (uint32_t)(tokr * 128 + ks * 64 + kg * 16) ^ ((uint32_t)(tokr & 7) << 4);
        bfr[tt] = *(const s16x8*)(asmb + ad);
      }
#pragma unroll
      for (int et = 0; et < 8; et++) {
        s16x8 af = *(const s16x8*)(CVbf + (size_t)(E0 + et * 16 + ln) * 64 + ks * 32 + kg * 8);
#pragma unroll
        for (int tt = 0; tt < 2; tt++) acc[et][tt] = MFMA(af, bfr[tt], acc[et][tt]);
      }
    }
    // E4: h' = x + attn (b64 RMW in xs) + LN1 partial stats from registers
#pragma unroll
    for (int tt = 0; tt < 2; tt++) { st[tt] = 0.f; sq[tt] = 0.f; }
#pragma unroll
    for (int et = 0; et < 8; et++)
#pragma unroll
      for (int tt = 0; tt < 2; tt++) {
        int tokr = tt * 16 + ln;
        int d = E0 + et * 16 + kg * 4;
        uint32_t ad = (uint32_t)(tokr * 2048 + d * 2) ^ ((uint32_t)(tokr & 7) << 4);
        s16x4 xv = *(const s16x4*)(xs + ad);
        s16x4 hv;
#pragma unroll
        for (int r = 0; r < 4; r++) {
          float h = bf2f((uint16_t)xv[r]) + acc[et][tt][r];
          st[tt] += h; sq[tt] += h * h;
          hv[r] = (short)f2bf(h);
        }
        *(s16x4*)(xs + ad) = hv;
      }
#pragma unroll
    for (int tt = 0; tt < 2; tt++) {
      st[tt] += __shfl_xor(st[tt], 16); st[tt] += __shfl_xor(st[tt], 32);
      sq[tt] += __shfl_xor(sq[tt], 16); sq[tt] += __shfl_xor(sq[tt], 32);
    }
    if (kg == 0) {
#pragma unroll
      for (int tt = 0; tt < 2; tt++) part[w * 32 + tt * 16 + ln] = float2{st[tt], sq[tt]};
    }
  }
  __syncthreads();
  if (tid < 32) {
    float s = 0.f, q = 0.f;
#pragma unroll
    for (int ww = 0; ww < 8; ww++) { float2 p = part[ww * 32 + tid]; s += p.x; q += p.y; }
    float mean = s * (1.0f / 1024.0f);
    float var  = fmaxf((q - 1024.0f * mean * mean) * (1.0f / 1023.0f), 0.f);
    stats[tid * 2] = mean;
    stats[tid * 2 + 1] = 1.0f / (sqrtf(var) + 1e-6f);
  }
  __syncthreads();

  // ---- P6: conv'[e][tok] = (g1*Wc) @ h'^T (K=1024), LN1 via u/vb
  {
    f32x4 acc[8][2];
#pragma unroll
    for (int et = 0; et < 8; et++)
#pragma unroll
      for (int tt = 0; tt < 2; tt++) acc[et][tt] = f32x4{0.f, 0.f, 0.f, 0.f};
    for (int ks = 0; ks < 32; ks++) {
      s16x8 bfr[2];
#pragma unroll
      for (int tt = 0; tt < 2; tt++) {
        int tokr = tt * 16 + ln;
        uint32_t ad = (uint32_t)(tokr * 2048 + ks * 64 + kg * 16) ^ ((uint32_t)(tokr & 7) << 4);
        bfr[tt] = *(const s16x8*)(xs + ad);
      }
#pragma unroll
      for (int et = 0; et < 8; et++) {
        s16x8 af = *(const s16x8*)(Wpbf + (size_t)(E0 + et * 16 + ln) * 1024 + ks * 32 + kg * 8);
#pragma unroll
        for (int tt = 0; tt < 2; tt++) acc[et][tt] = MFMA(af, bfr[tt], acc[et][tt]);
      }
    }
    __syncthreads();  // all waves done reading h' before overwrite with r
    // E6: conv -> leaky -> r = LN1(h') + act ; r -> xs bf16 ; LN2 partials
#pragma unroll
    for (int tt = 0; tt < 2; tt++) { st[tt] = 0.f; sq[tt] = 0.f; }
#pragma unroll
    for (int et = 0; et < 8; et++) {
      int e0 = E0 + et * 16 + kg * 4;
      float4 u4 = *(const float4*)(u + e0);
      float4 v4 = *(const float4*)(vb + e0);
      float4 gg = *(const float4*)(g1 + e0);
      float4 bb = *(const float4*)(be1 + e0);
      const float *uf = (const float*)&u4, *vf = (const float*)&v4;
      const float *gf = (const float*)&gg, *bf = (const float*)&bb;
#pragma unroll
      for (int tt = 0; tt < 2; tt++) {
        int tokr = tt * 16 + ln;
        float mean = stats[tokr * 2], rinv = stats[tokr * 2 + 1];
        uint32_t ad = (uint32_t)(tokr * 2048 + e0 * 2) ^ ((uint32_t)(tokr & 7) << 4);
        s16x4 hv = *(const s16x4*)(xs + ad);
        s16x4 rv;
#pragma unroll
        for (int r = 0; r < 4; r++) {
          float conv = acc[et][tt][r] * rinv - rinv * mean * uf[r] + vf[r];
          float act  = conv > 0.f ? conv : 0.01f * conv;
          float h    = gf[r] * (bf2f((uint16_t)hv[r]) - mean) * rinv + bf[r];
          float rr   = h + act;
          rv[r] = (short)f2bf(rr);
          st[tt] += rr; sq[tt] += rr * rr;
        }
        *(s16x4*)(xs + ad) = rv;
      }
    }
#pragma unroll
    for (int tt = 0; tt < 2; tt++) {
      st[tt] += __shfl_xor(st[tt], 16); st[tt] += __shfl_xor(st[tt], 32);
      sq[tt] += __shfl_xor(sq[tt], 16); sq[tt] += __shfl_xor(sq[tt], 32);
    }
    if (kg == 0) {
#pragma unroll
      for (int tt = 0; tt < 2; tt++) part[w * 32 + tt * 16 + ln] = float2{st[tt], sq[tt]};
    }
  }
  __syncthreads();
  if (tid < 32) {
    float s = 0.f, q = 0.f;
#pragma unroll
    for (int ww = 0; ww < 8; ww++) { float2 p = part[ww * 32 + tid]; s += p.x; q += p.y; }
    float mean = s * (1.0f / 1024.0f);
    float var  = fmaxf((q - 1024.0f * mean * mean) * (1.0f / 1023.0f), 0.f);
    stats[tid * 2] = mean;
    stats[tid * 2 + 1] = 1.0f / (sqrtf(var) + 1e-6f);
  }
  __syncthreads();

  // ---- P8: LN2 + fully-coalesced f32 store (8192 float4-granules, 16/thread)
  {
#pragma unroll
    for (int i = 0; i < 16; i++) {
      int g = tid + i * NT;
      int row = g >> 8, c4 = g & 255;
      uint32_t ad = (uint32_t)(row * 2048 + c4 * 8) ^ ((uint32_t)(row & 7) << 4);
      s16x4 vv = *(const s16x4*)(xs + ad);
      float mean = stats[row * 2], rinv = stats[row * 2 + 1];
      float4 gg = *(const float4*)(g2 + c4 * 4);
      float4 bb = *(const float4*)(be2 + c4 * 4);
      float4 o;
      o.x = gg.x * (bf2f((uint16_t)vv[0]) - mean) * rinv + bb.x;
      o.y = gg.y * (bf2f((uint16_t)vv[1]) - mean) * rinv + bb.y;
      o.z = gg.z * (bf2f((uint16_t)vv[2]) - mean) * rinv + bb.z;
      o.w = gg.w * (bf2f((uint16_t)vv[3]) - mean) * rinv + bb.w;
      *(float4*)(out + (tok0 + row) * 1024 + c4 * 4) = o;
    }
  }
}

extern "C" void kernel_launch(void* const* d_in, const int* in_sizes, int n_in,
                              void* d_out, int out_size, void* d_ws, size_t ws_size,
                              hipStream_t stream) {
  const float* x   = (const float*)d_in[0];
  const int*   msk = (const int*)d_in[1];
  const float* WQ  = (const float*)d_in[2];
  const float* bQ  = (const float*)d_in[3];
  const float* CK  = (const float*)d_in[4];
  const float* CV  = (const float*)d_in[5];
  const float* g1  = (const float*)d_in[6];
  const float* be1 = (const float*)d_in[7];
  const float* Wc  = (const float*)d_in[8];
  const float* bc  = (const float*)d_in[9];
  const float* g2  = (const float*)d_in[10];
  const float* be2 = (const float*)d_in[11];
  float* out = (float*)d_out;

  char* ws = (char*)d_ws;
  uint16_t* Wpbf = (uint16_t*)ws;                 // 2 MiB
  uint16_t* MbfT = (uint16_t*)(ws + 2097152);     // 128 KiB
  uint16_t* CVbf = (uint16_t*)(ws + 2228224);     // 128 KiB
  float*    s0   = (float*)(ws + 2359296);        // 256 B
  float*    u    = (float*)(ws + 2359552);        // 4 KiB
  float*    vb   = (float*)(ws + 2363648);        // 4 KiB

  (void)hipFuncSetAttribute((const void*)fused_main,
                            hipFuncAttributeMaxDynamicSharedMemorySize, 78080);

  k0_all<<<1409, 256, 0, stream>>>(WQ, bQ, CK, CV, Wc, g1, be1, bc,
                                   MbfT, s0, CVbf, Wpbf, u, vb);
  fused_main<<<1024, NT, 78080, stream>>>(x, msk, s0, MbfT, CVbf, Wpbf,
                                          u, vb, g1, be1, g2, be2, out);
}